// Round 8
// baseline (481.405 us; speedup 1.0000x reference)
//
#include <hip/hip_runtime.h>

// ---------------------------------------------------------------------------
// HierarchicalCodebookGrounding — round 14: 8 dispatches -> 4, zero memsets.
// r7 ledger: fused_pre 103.5 + attn 83 + ~25us of tail compute, yet total
// 395 -> ~180us rides on 8 dispatch boundaries (~20us each; tail kernels run
// at 16-128 blocks so every boundary pays launch+ramp+drain).
// Changes:
//   - memsets deleted: pospool -> plain partial stores ppart/cpart; combine
//     -> plain zpart stores (zeros where slice empty); gate reduces both.
//   - hnorm FUSED into combine: each (b,j) block computes all 672 row norms
//     from H2 partials (8x redundant, L2-resident ~3us), cascade in LDS,
//     then its 84-row z-slice reading H2[0]+H2[1] directly. H never
//     materialized; wraw/lsum/H arrays deleted.
// Chain: fused_pre -> attn_fused -> combine -> gate.
//   fused_pre  : Kpack / XTpack / ppart,cpart / Qpack in ONE launch
//   attn_fused : r6 structure — 2048-n slices, plain-store partials (83us)
//   combine    : norms + cascade + sliced z-sums -> zpart (grid 16x8)
//   gate       : zpart/ppart reduce + MLP + level combine + out proj + LN
// ---------------------------------------------------------------------------

#define DEV static __device__ __forceinline__

typedef short bf16x8 __attribute__((ext_vector_type(8)));
typedef float f32x4 __attribute__((ext_vector_type(4)));
typedef unsigned short u16x8 __attribute__((ext_vector_type(8)));

DEV float bf2f(unsigned short u) {
  return __uint_as_float(((unsigned int)u) << 16);
}
DEV unsigned short f2bf(float f) {
  unsigned int x = __float_as_uint(f);
  unsigned int r = (x + 0x7fffu + ((x >> 16) & 1u)) >> 16;
  return (unsigned short)r;
}

// async global->LDS, 16B per lane; LDS dest = wave-uniform base + lane*16
DEV void gl2lds16(const void* g, void* l) {
  __builtin_amdgcn_global_load_lds(
      (const __attribute__((address_space(1))) unsigned int*)g,
      (__attribute__((address_space(3))) unsigned int*)l, 16, 0, 0);
}

DEV bf16x8 pack8(const float4 a, const float4 b) {
  bf16x8 r;
  r[0] = (short)f2bf(a.x); r[1] = (short)f2bf(a.y);
  r[2] = (short)f2bf(a.z); r[3] = (short)f2bf(a.w);
  r[4] = (short)f2bf(b.x); r[5] = (short)f2bf(b.y);
  r[6] = (short)f2bf(b.z); r[7] = (short)f2bf(b.w);
  return r;
}

// packed fragment address (elements): row-tile rt, k-step ks
// layout: [rt][ks(8 per 256k)][64][8]; slot = (row&15) + 16*((k>>3)&3)
DEV size_t pk_off(int rt, int ks) { return ((size_t)rt * 8 + ks) * 512; }

// ---------------------------------------------------------------------------
// fused_pre: one launch for all independent pre-passes.
//   g in [0,1024)      : kproj  — Kpack = bf16(X @ k_w^T + k_b), 128x128 tile
//   g in [1024,5120)   : xT     — XTpack = bf16(X^T) packed
//   g in [5120,5632)   : pospool— masked position partial sums (plain store)
//   g in [5632,6336)   : qproj  — Qpack = bf16(code @ W^T + b)
// Shared union: 36864B (kproj As+Bs). Branches are block-uniform.
// ---------------------------------------------------------------------------
__global__ __launch_bounds__(256) void fused_pre(
    const float* __restrict__ X, const float* __restrict__ k_w,
    const float* __restrict__ k_b, unsigned short* __restrict__ Kp,
    unsigned short* __restrict__ XTp, const float* __restrict__ positions,
    const unsigned char* __restrict__ mask, float* __restrict__ ppart,
    float* __restrict__ cpart, const float* __restrict__ cat_codes,
    const float* __restrict__ type_codes, const float* __restrict__ var_codes,
    const float* __restrict__ sp_codes, const float* __restrict__ cat_w,
    const float* __restrict__ cat_b, const float* __restrict__ type_w,
    const float* __restrict__ type_b, const float* __restrict__ var_w,
    const float* __restrict__ var_b, const float* __restrict__ sp_w,
    const float* __restrict__ sp_b, unsigned short* __restrict__ Qp) {
  __shared__ __align__(16) char smem[36864];
  const int g = blockIdx.x;
  const int t = threadIdx.x;

  if (g < 1024) {
    // ---------------- kproj branch ----------------
    unsigned short* As = (unsigned short*)smem;           // 128*72
    unsigned short* Bs = (unsigned short*)(smem + 18432); // 128*72
    const int m0 = (g >> 1) * 128, c0 = (g & 1) * 128;
    const int l = t & 63, w = t >> 6;
    const int wm = (w & 1) * 64, wn = (w >> 1) * 64;
    const f32x4 zero = {0.f, 0.f, 0.f, 0.f};
    f32x4 acc[4][4];
#pragma unroll
    for (int i = 0; i < 4; ++i)
#pragma unroll
      for (int j = 0; j < 4; ++j) acc[i][j] = zero;
    const int rr = t >> 3, cc = (t & 7) * 8;
    for (int kc = 0; kc < 256; kc += 64) {
      __syncthreads();
#pragma unroll
      for (int p = 0; p < 4; ++p) {
        const int r = p * 32 + rr;
        const float* xs = &X[(size_t)(m0 + r) * 256 + kc + cc];
        const float4 a0 = *(const float4*)&xs[0];
        const float4 a1 = *(const float4*)&xs[4];
        *(bf16x8*)&As[r * 72 + cc] = pack8(a0, a1);
        const float* wsrc = &k_w[(size_t)(c0 + r) * 256 + kc + cc];
        const float4 b0 = *(const float4*)&wsrc[0];
        const float4 b1 = *(const float4*)&wsrc[4];
        *(bf16x8*)&Bs[r * 72 + cc] = pack8(b0, b1);
      }
      __syncthreads();
#pragma unroll
      for (int ks = 0; ks < 2; ++ks) {
        const int koff = ks * 32 + ((l >> 4) & 3) * 8;
        bf16x8 a[4], b[4];
#pragma unroll
        for (int f = 0; f < 4; ++f)
          a[f] = *(const bf16x8*)&As[(wm + f * 16 + (l & 15)) * 72 + koff];
#pragma unroll
        for (int f = 0; f < 4; ++f)
          b[f] = *(const bf16x8*)&Bs[(wn + f * 16 + (l & 15)) * 72 + koff];
#pragma unroll
        for (int i = 0; i < 4; ++i)
#pragma unroll
          for (int j = 0; j < 4; ++j)
            acc[i][j] = __builtin_amdgcn_mfma_f32_16x16x32_bf16(
                a[i], b[j], acc[i][j], 0, 0, 0);
      }
    }
    const int q = (l >> 4) & 3;
#pragma unroll
    for (int j = 0; j < 4; ++j) {
      const int c = c0 + wn + j * 16 + (l & 15);
      const float bv = k_b[c];
#pragma unroll
      for (int i = 0; i < 4; ++i) {
        const int mrow = m0 + wm + i * 16 + q * 4;
#pragma unroll
        for (int r = 0; r < 4; ++r) {
          const int m = mrow + r;
          Kp[pk_off(m >> 4, c >> 5) + ((m & 15) + 16 * ((c >> 3) & 3)) * 8 +
             (c & 7)] = f2bf(acc[i][j][r] + bv);
        }
      }
    }
  } else if (g < 5120) {
    // ---------------- xT branch ----------------
    float (*Ls)[65] = (float (*)[65])smem;  // 64x65 floats = 16640B
    const int gg = g - 1024;
    const int b = gg >> 8;
    const int td = (gg >> 6) & 3;
    const int tn = gg & 63;
    const int nl = t >> 2, dp = (t & 3) * 16;
    const float* src =
        X + ((size_t)b * 4096 + tn * 64 + nl) * 256 + td * 64 + dp;
#pragma unroll
    for (int v = 0; v < 4; ++v) {
      const float4 x = *(const float4*)&src[v * 4];
      Ls[nl][dp + v * 4 + 0] = x.x;
      Ls[nl][dp + v * 4 + 1] = x.y;
      Ls[nl][dp + v * 4 + 2] = x.z;
      Ls[nl][dp + v * 4 + 3] = x.w;
    }
    __syncthreads();
    const int dl = t >> 2, np = (t & 3) * 16;
    u16x8 h0, h1;
#pragma unroll
    for (int j = 0; j < 8; ++j) h0[j] = f2bf(Ls[np + j][dl]);
#pragma unroll
    for (int j = 0; j < 8; ++j) h1[j] = f2bf(Ls[np + 8 + j][dl]);
    const int d = td * 64 + dl;
    const int n0g = tn * 64 + np;
    const int n1g = n0g + 8;
    unsigned short* dst = XTp + (size_t)b * 1048576;
    const size_t o0 = (((size_t)(d >> 4) * 128) + (n0g >> 5)) * 512 +
                      ((d & 15) + 16 * ((n0g >> 3) & 3)) * 8;
    const size_t o1 = (((size_t)(d >> 4) * 128) + (n1g >> 5)) * 512 +
                      ((d & 15) + 16 * ((n1g >> 3) & 3)) * 8;
    *(u16x8*)&dst[o0] = h0;
    *(u16x8*)&dst[o1] = h1;
  } else if (g < 5632) {
    // ---------------- pospool branch (plain partial stores) ----------------
    float4* red4 = (float4*)smem;                 // 256 float4 = 4096B
    float* redc = (float*)(smem + 4096);          // 4 floats
    const int gg = g - 5120;
    const int b = gg >> 5, seg = gg & 31;
    const int dg = t & 63;
    const int nl = t >> 6;
    const int n0 = seg * 128;
    float4 acc = make_float4(0.f, 0.f, 0.f, 0.f);
    float c = 0.f;
    const float* pb = positions + (size_t)b * 4096 * 256;
    for (int j = 0; j < 32; ++j) {
      const int n = n0 + j * 4 + nl;
      const float mf = mask[(size_t)b * 4096 + n] ? 1.f : 0.f;
      const float4 v = *(const float4*)&pb[(size_t)n * 256 + dg * 4];
      acc.x = fmaf(mf, v.x, acc.x);
      acc.y = fmaf(mf, v.y, acc.y);
      acc.z = fmaf(mf, v.z, acc.z);
      acc.w = fmaf(mf, v.w, acc.w);
      c += mf;
    }
    red4[t] = acc;
    if (dg == 0) redc[nl] = c;
    __syncthreads();
    if (t < 64) {
      float4 s = red4[t];
      const float4 s1 = red4[t + 64], s2 = red4[t + 128], s3 = red4[t + 192];
      s.x += s1.x + s2.x + s3.x;
      s.y += s1.y + s2.y + s3.y;
      s.z += s1.z + s2.z + s3.z;
      s.w += s1.w + s2.w + s3.w;
      *(float4*)&ppart[(size_t)(b * 32 + seg) * 256 + t * 4] = s;
      if (t == 0) cpart[b * 32 + seg] = redc[0] + redc[1] + redc[2] + redc[3];
    }
  } else {
    // ---------------- qproj branch ----------------
    float* xs = (float*)smem;  // 256 floats
    const int m = g - 5632;
    const size_t off = pk_off(m >> 4, t >> 5) +
                       ((m & 15) + 16 * ((t >> 3) & 3)) * 8 + (t & 7);
    if (m >= 672) {
      Qp[off] = 0;
      return;
    }
    const float* code;
    const float* W;
    const float* bias;
    if (m < 16)       { code = cat_codes  + m * 256;         W = cat_w;  bias = cat_b; }
    else if (m < 144) { code = type_codes + (m - 16) * 256;  W = type_w; bias = type_b; }
    else if (m < 656) { code = var_codes  + (m - 144) * 256; W = var_w;  bias = var_b; }
    else              { code = sp_codes   + (m - 656) * 256; W = sp_w;   bias = sp_b; }
    xs[t] = code[t];
    __syncthreads();
    float a = bias[t];
    const float* wr = W + (size_t)t * 256;
    for (int k = 0; k < 256; k += 4) {
      const float4 w = *(const float4*)&wr[k];
      a = fmaf(w.x, xs[k], a);
      a = fmaf(w.y, xs[k + 1], a);
      a = fmaf(w.z, xs[k + 2], a);
      a = fmaf(w.w, xs[k + 3], a);
    }
    Qp[off] = f2bf(a);
  }
}

// ---------------------------------------------------------------------------
// attn_fused: grid (32 combos, 11 m-tiles). combo = b*2 + n-slice(2048).
// Per 64-n chunk (32 chunks): K staged 32KB -> LDS via DMA (dbuf, drained by
// next-chunk barrier, hidden behind PV); S from LDS; P via padded LDS.
// Epilogue: PLAIN STORES into per-slice partials H2[nsl]/lsum2[nsl].
// ---------------------------------------------------------------------------
__global__ __launch_bounds__(256, 2) void attn_fused(
    const unsigned short* __restrict__ Qp, const unsigned short* __restrict__ Kp,
    const unsigned short* __restrict__ XTp,
    const unsigned char* __restrict__ mask, float* __restrict__ H2,
    float* __restrict__ lsum2) {
  __shared__ __align__(16) unsigned short Ks[2][16384];  // 2 x 32KB
  __shared__ __align__(16) unsigned short Plds[64 * 72];
  __shared__ unsigned char msk[2048];
  const int combo = blockIdx.x;
  const int m0 = blockIdx.y * 64;
  const int b = combo >> 1;
  const int nsl = combo & 1;
  const int nbase = nsl * 2048;
  const int t = threadIdx.x, l = t & 63, w = t >> 6;
  const int l15 = l & 15, q = l >> 4;
  ((uint2*)msk)[t] = ((const uint2*)(mask + (size_t)b * 4096 + nbase))[t];
  const int mt_g = (m0 >> 4) + w;
  bf16x8 qf[8];
#pragma unroll
  for (int ks = 0; ks < 8; ++ks)
    qf[ks] = *(const bf16x8*)&Qp[pk_off(mt_g, ks) + l * 8];
  const f32x4 zero = {0.f, 0.f, 0.f, 0.f};
  f32x4 accO[4][4];
#pragma unroll
  for (int i = 0; i < 4; ++i)
#pragma unroll
    for (int j = 0; j < 4; ++j) accO[i][j] = zero;
  f32x4 rs = zero;
  const unsigned short* XTb = XTp + (size_t)b * 1048576;
  // K chunk c is 32KB contiguous at Kp + (b*256 + nbase/16 + 4c)*4096 elems.
  const unsigned short* Kchunk0 = Kp + ((size_t)b * 256 + (nbase >> 4)) * 4096;
  // prologue: DMA chunk 0 into Ks[0]; wave w stages its 8KB quarter
#pragma unroll
  for (int i = 0; i < 8; ++i)
    gl2lds16(Kchunk0 + (w * 8 + i) * 512 + l * 8, &Ks[0][(w * 8 + i) * 512]);
  for (int c = 0; c < 32; ++c) {
    const int cur = c & 1;
    __syncthreads();  // C: drains DMA(c) (vmcnt0) + all waves past PV(c-1)
    // ---- prefetch PV B-fragments (independent; consumed after barrier B) --
    const int nst0 = (nbase >> 5) + c * 2;
    bf16x8 xf[2][4];
#pragma unroll
    for (int ks2 = 0; ks2 < 2; ++ks2)
#pragma unroll
      for (int dj = 0; dj < 4; ++dj)
        xf[ks2][dj] = *(const bf16x8*)&XTb[((size_t)(4 * w + dj) * 128 +
                                            nst0 + ks2) * 512 + l * 8];
    // ---- S phase from LDS ----
    f32x4 accS[4];
#pragma unroll
    for (int f = 0; f < 4; ++f) accS[f] = zero;
#pragma unroll
    for (int ks = 0; ks < 8; ++ks) {
      bf16x8 kf[4];
#pragma unroll
      for (int f = 0; f < 4; ++f)
        kf[f] = *(const bf16x8*)&Ks[cur][(f * 8 + ks) * 512 + l * 8];
#pragma unroll
      for (int f = 0; f < 4; ++f)
        accS[f] = __builtin_amdgcn_mfma_f32_16x16x32_bf16(qf[ks], kf[f],
                                                          accS[f], 0, 0, 0);
    }
    // ---- epilogue: exp + P -> LDS (C-layout rows, stride 72) ----
#pragma unroll
    for (int f = 0; f < 4; ++f) {
      const bool mk = msk[c * 64 + f * 16 + l15] != 0;
#pragma unroll
      for (int r = 0; r < 4; ++r) {
        float s = accS[f][r] * 0.0625f;
        s = fminf(fmaxf(s, -50.f), 50.f);
        if (!mk) s = -50.f;
        const float e = __expf(s);
        Plds[(w * 16 + q * 4 + r) * 72 + f * 16 + l15] = f2bf(e);
        rs[r] += e;
      }
    }
    __syncthreads();  // B: Plds visible (also drains xf loads - needed next)
    // ---- issue DMA for chunk c+1 (drains at next C, hidden behind PV) ----
    if (c < 31) {
      const unsigned short* src = Kchunk0 + (size_t)(c + 1) * 16384;
      unsigned short* dst = &Ks[1 - cur][0];
#pragma unroll
      for (int i = 0; i < 8; ++i)
        gl2lds16(src + (w * 8 + i) * 512 + l * 8, dst + (w * 8 + i) * 512);
    }
    // ---- PV phase ----
#pragma unroll
    for (int ks2 = 0; ks2 < 2; ++ks2) {
      bf16x8 pf[4];
#pragma unroll
      for (int mt = 0; mt < 4; ++mt)
        pf[mt] = *(const bf16x8*)&Plds[(mt * 16 + l15) * 72 + ks2 * 32 + q * 8];
#pragma unroll
      for (int mt = 0; mt < 4; ++mt)
#pragma unroll
        for (int dj = 0; dj < 4; ++dj)
          accO[mt][dj] = __builtin_amdgcn_mfma_f32_16x16x32_bf16(
              pf[mt], xf[ks2][dj], accO[mt][dj], 0, 0, 0);
    }
  }
  // ---- lsum partial: reduce rs over the 16 lanes sharing each row ----
  float* lpart = lsum2 + (size_t)(nsl * 16 + b) * 672;
#pragma unroll
  for (int r = 0; r < 4; ++r) {
    float v = rs[r];
    v += __shfl_xor(v, 1, 64);
    v += __shfl_xor(v, 2, 64);
    v += __shfl_xor(v, 4, 64);
    v += __shfl_xor(v, 8, 64);
    const int m = m0 + w * 16 + q * 4 + r;
    if (l15 == 0 && m < 672) lpart[m] = v;
  }
  // ---- O partial: plain stores into H2[nsl] (no atomics) ----
  float* Hpart = H2 + (size_t)(nsl * 16 + b) * 672 * 256;
#pragma unroll
  for (int mt = 0; mt < 4; ++mt) {
    const int mbase = m0 + mt * 16 + q * 4;
#pragma unroll
    for (int dj = 0; dj < 4; ++dj) {
      const int d = w * 64 + dj * 16 + l15;
#pragma unroll
      for (int r = 0; r < 4; ++r) {
        const int m = mbase + r;
        if (m < 672) Hpart[(size_t)m * 256 + d] = accO[mt][dj][r];
      }
    }
  }
}

DEV float wave_max(float v) {
#pragma unroll
  for (int m = 1; m < 64; m <<= 1) v = fmaxf(v, __shfl_xor(v, m, 64));
  return v;
}
DEV float wave_sum(float v) {
#pragma unroll
  for (int m = 1; m < 64; m <<= 1) v += __shfl_xor(v, m, 64);
  return v;
}

// ---------------------------------------------------------------------------
// combine: grid (16, 8). Phase 1: every block computes all 672 row norms
// from H2 partials (L2-resident) + lsum fold -> wr/linv in LDS (hnorm fused;
// H never materialized). Phase 2: wsp cascade. Phase 3: the block's 84-m
// z-slice reading H2[0]+H2[1], plain stores to zpart (zeros where empty).
// ---------------------------------------------------------------------------
__global__ __launch_bounds__(256) void combine_kern(
    const float* __restrict__ H2, const float* __restrict__ lsum2,
    const float* __restrict__ log_tau, float* __restrict__ zpart) {
  const int b = blockIdx.x, j = blockIdx.y, t = threadIdx.x;
  const int l = t & 63, w = t >> 6;
  __shared__ float wr[672];
  __shared__ float wsp[672];
  __shared__ float linv[672];
  const float tau = fminf(fmaxf(expf(log_tau[0]) + 0.1f, 0.1f), 2.0f);
  const float* Ha = H2 + (size_t)b * 672 * 256;
  const float* Hc = H2 + (size_t)(16 + b) * 672 * 256;
  // ---- phase 1: norms of (H2[0]+H2[1]) rows; wr = ||.||/(lsum*tau) ----
  for (int m = w; m < 672; m += 4) {
    const float4 va = *(const float4*)&Ha[(size_t)m * 256 + l * 4];
    const float4 vb = *(const float4*)&Hc[(size_t)m * 256 + l * 4];
    const float sx = va.x + vb.x, sy = va.y + vb.y;
    const float sz = va.z + vb.z, sw = va.w + vb.w;
    float ss = sx * sx + sy * sy + sz * sz + sw * sw;
#pragma unroll
    for (int s = 1; s < 64; s <<= 1) ss += __shfl_xor(ss, s, 64);
    if (l == 0) {
      const float lt = lsum2[b * 672 + m] + lsum2[(16 + b) * 672 + m];
      const float li = 1.0f / lt;
      wr[m] = sqrtf(ss) * li / tau;
      linv[m] = li;
    }
  }
  __syncthreads();
  // ---- phase 2: cascade ----
  {
    const float v = (l < 16) ? wr[l] : -1e30f;
    const float mx = wave_max(v);
    const float e = (l < 16) ? expf(wr[l] - mx) : 0.f;
    const float s = wave_sum(e);
    float ww = e / s;
    ww = (ww > 0.1f) ? ww : 0.f;
    const float s2 = wave_sum(ww);
    if (l < 16) wsp[l] = ww / (s2 + 1e-8f);
  }
  __syncthreads();
  {
    const float L0 = wr[16 + l] * wsp[l >> 3];
    const float L1 = wr[16 + 64 + l] * wsp[(64 + l) >> 3];
    const float mx = wave_max(fmaxf(L0, L1));
    const float e0 = expf(L0 - mx), e1 = expf(L1 - mx);
    const float s = wave_sum(e0 + e1);
    float w0 = e0 / s, w1 = e1 / s;
    w0 = (w0 > 0.05f) ? w0 : 0.f;
    w1 = (w1 > 0.05f) ? w1 : 0.f;
    const float s2 = wave_sum(w0 + w1);
    const float inv2 = 1.f / (s2 + 1e-8f);
    wsp[16 + l] = w0 * inv2;
    wsp[16 + 64 + l] = w1 * inv2;
  }
  __syncthreads();
  {
    float Lv[8];
    float lm = -1e30f;
#pragma unroll
    for (int jj = 0; jj < 8; ++jj) {
      const int i = l * 8 + jj;
      Lv[jj] = wr[144 + i] * wsp[16 + (i >> 2)];
      lm = fmaxf(lm, Lv[jj]);
    }
    const float mx = wave_max(lm);
    float ls = 0.f;
#pragma unroll
    for (int jj = 0; jj < 8; ++jj) {
      Lv[jj] = expf(Lv[jj] - mx);
      ls += Lv[jj];
    }
    const float s = wave_sum(ls);
    const float inv = 1.f / s;
    float ls2 = 0.f;
#pragma unroll
    for (int jj = 0; jj < 8; ++jj) {
      float ww = Lv[jj] * inv;
      ww = (ww > 0.025f) ? ww : 0.f;
      Lv[jj] = ww;
      ls2 += ww;
    }
    const float s2 = wave_sum(ls2);
    const float inv2 = 1.f / (s2 + 1e-8f);
#pragma unroll
    for (int jj = 0; jj < 8; ++jj) wsp[144 + l * 8 + jj] = Lv[jj] * inv2;
  }
  __syncthreads();
  {
    const float v = (l < 16) ? wr[656 + l] : -1e30f;
    const float mx = wave_max(v);
    const float e = (l < 16) ? expf(wr[656 + l] - mx) : 0.f;
    const float s = wave_sum(e);
    float ww = e / s;
    ww = (ww > 0.1f) ? ww : 0.f;
    const float s2 = wave_sum(ww);
    if (l < 16) wsp[656 + l] = ww / (s2 + 1e-8f);
  }
  __syncthreads();
  // fold normalization: weight = wsp[m] / lsum[b][m]
  for (int i = t; i < 672; i += 256) wsp[i] *= linv[i];
  __syncthreads();
  // ---- phase 3: this block's 84-m slice of the z-sums ----
  const int s0 = j * 84, s1 = s0 + 84;
  const int Llo[4] = {0, 16, 144, 656};
  const int Lhi[4] = {16, 144, 656, 672};
#pragma unroll
  for (int lv = 0; lv < 4; ++lv) {
    const int lo = max(s0, Llo[lv]);
    const int hi = min(s1, Lhi[lv]);
    float z = 0.f;
    for (int m = lo; m < hi; ++m)
      z = fmaf(wsp[m], Ha[(size_t)m * 256 + t] + Hc[(size_t)m * 256 + t], z);
    zpart[(((size_t)b * 8 + j) * 4 + lv) * 256 + t] = z;  // 0 where empty
  }
}

// ---------------------------------------------------------------------------
// gate: reduce zpart/ppart/cpart, pos-gate MLP, level combine, out proj, LN.
// grid 16.
// ---------------------------------------------------------------------------
__global__ __launch_bounds__(256) void gate_kern(
    const float* __restrict__ zpart, const float* __restrict__ ppart,
    const float* __restrict__ cpart, const float* __restrict__ g1_w,
    const float* __restrict__ g1_b, const float* __restrict__ g2_w,
    const float* __restrict__ g2_b, const float* __restrict__ out_w,
    const float* __restrict__ out_b, const float* __restrict__ ln_g,
    const float* __restrict__ ln_b, const float* __restrict__ lvlw,
    float* __restrict__ out) {
  const int b = blockIdx.x, t = threadIdx.x;
  __shared__ float gin[512];
  __shared__ float hb[256];
  __shared__ float zc[256];
  __shared__ float red[256];
  // ---- reduce zpart over j ----
  float zv[4];
#pragma unroll
  for (int lv = 0; lv < 4; ++lv) {
    float z = 0.f;
#pragma unroll
    for (int jj = 0; jj < 8; ++jj)
      z += zpart[(((size_t)b * 8 + jj) * 4 + lv) * 256 + t];
    zv[lv] = z;
  }
  // ---- reduce ppart/cpart over seg ----
  float pa = 0.f, c = 0.f;
  for (int seg = 0; seg < 32; ++seg) {
    pa += ppart[(size_t)(b * 32 + seg) * 256 + t];
    c += cpart[b * 32 + seg];
  }
  c = fmaxf(c, 1.0f);
  gin[t] = zv[0];
  gin[256 + t] = pa / c;
  __syncthreads();
  float a = g1_b[t];
  const float* w1 = g1_w + (size_t)t * 512;
  for (int k = 0; k < 512; k += 4) {
    const float4 w = *(const float4*)&w1[k];
    a = fmaf(w.x, gin[k], a);
    a = fmaf(w.y, gin[k + 1], a);
    a = fmaf(w.z, gin[k + 2], a);
    a = fmaf(w.w, gin[k + 3], a);
  }
  const float hg = 0.5f * a * (1.0f + erff(a * 0.7071067811865475f));
  hb[t] = hg;
  __syncthreads();
  float a2 = g2_b[t];
  const float* w2 = g2_w + (size_t)t * 256;
  for (int k = 0; k < 256; k += 4) {
    const float4 w = *(const float4*)&w2[k];
    a2 = fmaf(w.x, hb[k], a2);
    a2 = fmaf(w.y, hb[k + 1], a2);
    a2 = fmaf(w.z, hb[k + 2], a2);
    a2 = fmaf(w.w, hb[k + 3], a2);
  }
  const float pg = 1.0f / (1.0f + expf(-a2));
  const float l0 = lvlw[0], l1 = lvlw[1], l2 = lvlw[2], l3 = lvlw[3];
  const float mx = fmaxf(fmaxf(l0, l1), fmaxf(l2, l3));
  const float e0 = expf(l0 - mx), e1 = expf(l1 - mx);
  const float e2 = expf(l2 - mx), e3 = expf(l3 - mx);
  const float einv = 1.0f / (e0 + e1 + e2 + e3);
  const float zmix =
      (e0 * zv[0] * pg + e1 * zv[1] + e2 * zv[2] + e3 * zv[3]) * einv;
  zc[t] = zmix;
  __syncthreads();
  float o = out_b[t];
  const float* wo = out_w + (size_t)t * 256;
  for (int k = 0; k < 256; k += 4) {
    const float4 w = *(const float4*)&wo[k];
    o = fmaf(w.x, zc[k], o);
    o = fmaf(w.y, zc[k + 1], o);
    o = fmaf(w.z, zc[k + 2], o);
    o = fmaf(w.w, zc[k + 3], o);
  }
  red[t] = o;
  __syncthreads();
  for (int s = 128; s > 0; s >>= 1) {
    if (t < s) red[t] += red[t + s];
    __syncthreads();
  }
  const float mu = red[0] / 256.f;
  __syncthreads();
  red[t] = o * o;
  __syncthreads();
  for (int s = 128; s > 0; s >>= 1) {
    if (t < s) red[t] += red[t + s];
    __syncthreads();
  }
  const float var = red[0] / 256.f - mu * mu;
  out[b * 256 + t] = (o - mu) * rsqrtf(var + 1e-5f) * ln_g[t] + ln_b[t];
}

// ---------------------------------------------------------------------------
// launch — 4 dispatches, 0 memsets.
// ---------------------------------------------------------------------------
extern "C" void kernel_launch(void* const* d_in, const int* in_sizes, int n_in,
                              void* d_out, int out_size, void* d_ws,
                              size_t ws_size, hipStream_t stream) {
  (void)in_sizes; (void)n_in; (void)out_size; (void)ws_size;
  const float* X          = (const float*)d_in[0];
  const float* positions  = (const float*)d_in[1];
  const float* cat_codes  = (const float*)d_in[2];
  const float* type_codes = (const float*)d_in[3];
  const float* var_codes  = (const float*)d_in[4];
  const float* sp_codes   = (const float*)d_in[5];
  const float* log_tau    = (const float*)d_in[6];
  const float* cat_w      = (const float*)d_in[7];
  const float* cat_b      = (const float*)d_in[8];
  const float* type_w     = (const float*)d_in[9];
  const float* type_b     = (const float*)d_in[10];
  const float* var_w      = (const float*)d_in[11];
  const float* var_b      = (const float*)d_in[12];
  const float* sp_w       = (const float*)d_in[13];
  const float* sp_b       = (const float*)d_in[14];
  const float* k_w        = (const float*)d_in[15];
  const float* k_b        = (const float*)d_in[16];
  const float* g1_w       = (const float*)d_in[17];
  const float* g1_b       = (const float*)d_in[18];
  const float* g2_w       = (const float*)d_in[19];
  const float* g2_b       = (const float*)d_in[20];
  const float* out_w      = (const float*)d_in[21];
  const float* out_b      = (const float*)d_in[22];
  const float* ln_g       = (const float*)d_in[23];
  const float* ln_b       = (const float*)d_in[24];
  const float* lvlw       = (const float*)d_in[25];
  const unsigned char* mask = (const unsigned char*)d_in[26];

  char* ws = (char*)d_ws;
  constexpr size_t O_KP  = 0;          // bf16 Kpack [4096][512]   = 33,554,432
  constexpr size_t O_XT  = 33554432;   // bf16 XTpack              = 33,554,432
  constexpr size_t O_QP  = 67108864;   // bf16 Qpack               = 360,448
  constexpr size_t O_H2  = 67469312;   // f32 H2 [2][16][672][256] = 22,020,096
  constexpr size_t O_L2  = 89489408;   // f32 lsum2 [2][16][672]   = 86,016
  constexpr size_t O_PP  = 89575424;   // f32 ppart [512][256]     = 524,288
  constexpr size_t O_CP  = 90099712;   // f32 cpart [512]          = 2,048
  constexpr size_t O_ZP  = 90101760;   // f32 zpart [16][8][4][256]= 524,288

  unsigned short* Kp  = (unsigned short*)(ws + O_KP);
  unsigned short* XTp = (unsigned short*)(ws + O_XT);
  unsigned short* Qp  = (unsigned short*)(ws + O_QP);
  float* H2           = (float*)(ws + O_H2);
  float* lsum2        = (float*)(ws + O_L2);
  float* ppart        = (float*)(ws + O_PP);
  float* cpart        = (float*)(ws + O_CP);
  float* zpart        = (float*)(ws + O_ZP);
  float* out          = (float*)d_out;

  // one launch for kproj (1024) + xT (4096) + pospool (512) + qproj (704)
  fused_pre<<<dim3(6336), 256, 0, stream>>>(
      X, k_w, k_b, Kp, XTp, positions, mask, ppart, cpart, cat_codes,
      type_codes, var_codes, sp_codes, cat_w, cat_b, type_w, type_b, var_w,
      var_b, sp_w, sp_b, Qp);

  attn_fused<<<dim3(32, 11), 256, 0, stream>>>(Qp, Kp, XTp, mask, H2, lsum2);

  combine_kern<<<dim3(16, 8), 256, 0, stream>>>(H2, lsum2, log_tau, zpart);

  gate_kern<<<dim3(16), 256, 0, stream>>>(zpart, ppart, cpart, g1_w, g1_b,
                                          g2_w, g2_b, out_w, out_b, ln_g,
                                          ln_b, lvlw, out);
}

// Round 9
// 383.023 us; speedup vs baseline: 1.2569x; 1.2569x over previous
//
#include <hip/hip_runtime.h>

// ---------------------------------------------------------------------------
// HierarchicalCodebookGrounding — round 15: kill the latency-bound tail.
// r8 found: combine's fused norms = 131us (grid 128, 2 waves/CU latency
// chain), and ledger closure shows gate ~= 150us ALL SESSION (grid 16,
// 1 wave/SIMD, chained matvecs at HBM latency).
// Changes:
//   - hnorm back to WIDE (grid 16x168 = 2688 blocks): wraw + linv from H2
//     partials; H never materialized.
//   - combine reverted to cascade-from-wraw (r5 structure) + z-slices
//     reading H2[0]+H2[1]; plain zpart stores.
//   - gate: 1024 threads/block: matvec rows split 4-way (32 float4 loads/
//     thread + LDS reduce), 16 waves/block = 4 waves/SIMD.
// Chain: fused_pre -> attn_fused -> hnorm -> combine -> gate. 0 memsets.
// ---------------------------------------------------------------------------

#define DEV static __device__ __forceinline__

typedef short bf16x8 __attribute__((ext_vector_type(8)));
typedef float f32x4 __attribute__((ext_vector_type(4)));
typedef unsigned short u16x8 __attribute__((ext_vector_type(8)));

DEV float bf2f(unsigned short u) {
  return __uint_as_float(((unsigned int)u) << 16);
}
DEV unsigned short f2bf(float f) {
  unsigned int x = __float_as_uint(f);
  unsigned int r = (x + 0x7fffu + ((x >> 16) & 1u)) >> 16;
  return (unsigned short)r;
}

// async global->LDS, 16B per lane; LDS dest = wave-uniform base + lane*16
DEV void gl2lds16(const void* g, void* l) {
  __builtin_amdgcn_global_load_lds(
      (const __attribute__((address_space(1))) unsigned int*)g,
      (__attribute__((address_space(3))) unsigned int*)l, 16, 0, 0);
}

DEV bf16x8 pack8(const float4 a, const float4 b) {
  bf16x8 r;
  r[0] = (short)f2bf(a.x); r[1] = (short)f2bf(a.y);
  r[2] = (short)f2bf(a.z); r[3] = (short)f2bf(a.w);
  r[4] = (short)f2bf(b.x); r[5] = (short)f2bf(b.y);
  r[6] = (short)f2bf(b.z); r[7] = (short)f2bf(b.w);
  return r;
}

// packed fragment address (elements): row-tile rt, k-step ks
// layout: [rt][ks(8 per 256k)][64][8]; slot = (row&15) + 16*((k>>3)&3)
DEV size_t pk_off(int rt, int ks) { return ((size_t)rt * 8 + ks) * 512; }

// ---------------------------------------------------------------------------
// fused_pre: one launch for all independent pre-passes.
//   g in [0,1024)      : kproj  — Kpack = bf16(X @ k_w^T + k_b), 128x128 tile
//   g in [1024,5120)   : xT     — XTpack = bf16(X^T) packed
//   g in [5120,5632)   : pospool— masked position partial sums (plain store)
//   g in [5632,6336)   : qproj  — Qpack = bf16(code @ W^T + b)
// ---------------------------------------------------------------------------
__global__ __launch_bounds__(256) void fused_pre(
    const float* __restrict__ X, const float* __restrict__ k_w,
    const float* __restrict__ k_b, unsigned short* __restrict__ Kp,
    unsigned short* __restrict__ XTp, const float* __restrict__ positions,
    const unsigned char* __restrict__ mask, float* __restrict__ ppart,
    float* __restrict__ cpart, const float* __restrict__ cat_codes,
    const float* __restrict__ type_codes, const float* __restrict__ var_codes,
    const float* __restrict__ sp_codes, const float* __restrict__ cat_w,
    const float* __restrict__ cat_b, const float* __restrict__ type_w,
    const float* __restrict__ type_b, const float* __restrict__ var_w,
    const float* __restrict__ var_b, const float* __restrict__ sp_w,
    const float* __restrict__ sp_b, unsigned short* __restrict__ Qp) {
  __shared__ __align__(16) char smem[36864];
  const int g = blockIdx.x;
  const int t = threadIdx.x;

  if (g < 1024) {
    // ---------------- kproj branch ----------------
    unsigned short* As = (unsigned short*)smem;           // 128*72
    unsigned short* Bs = (unsigned short*)(smem + 18432); // 128*72
    const int m0 = (g >> 1) * 128, c0 = (g & 1) * 128;
    const int l = t & 63, w = t >> 6;
    const int wm = (w & 1) * 64, wn = (w >> 1) * 64;
    const f32x4 zero = {0.f, 0.f, 0.f, 0.f};
    f32x4 acc[4][4];
#pragma unroll
    for (int i = 0; i < 4; ++i)
#pragma unroll
      for (int j = 0; j < 4; ++j) acc[i][j] = zero;
    const int rr = t >> 3, cc = (t & 7) * 8;
    for (int kc = 0; kc < 256; kc += 64) {
      __syncthreads();
#pragma unroll
      for (int p = 0; p < 4; ++p) {
        const int r = p * 32 + rr;
        const float* xs = &X[(size_t)(m0 + r) * 256 + kc + cc];
        const float4 a0 = *(const float4*)&xs[0];
        const float4 a1 = *(const float4*)&xs[4];
        *(bf16x8*)&As[r * 72 + cc] = pack8(a0, a1);
        const float* wsrc = &k_w[(size_t)(c0 + r) * 256 + kc + cc];
        const float4 b0 = *(const float4*)&wsrc[0];
        const float4 b1 = *(const float4*)&wsrc[4];
        *(bf16x8*)&Bs[r * 72 + cc] = pack8(b0, b1);
      }
      __syncthreads();
#pragma unroll
      for (int ks = 0; ks < 2; ++ks) {
        const int koff = ks * 32 + ((l >> 4) & 3) * 8;
        bf16x8 a[4], b[4];
#pragma unroll
        for (int f = 0; f < 4; ++f)
          a[f] = *(const bf16x8*)&As[(wm + f * 16 + (l & 15)) * 72 + koff];
#pragma unroll
        for (int f = 0; f < 4; ++f)
          b[f] = *(const bf16x8*)&Bs[(wn + f * 16 + (l & 15)) * 72 + koff];
#pragma unroll
        for (int i = 0; i < 4; ++i)
#pragma unroll
          for (int j = 0; j < 4; ++j)
            acc[i][j] = __builtin_amdgcn_mfma_f32_16x16x32_bf16(
                a[i], b[j], acc[i][j], 0, 0, 0);
      }
    }
    const int q = (l >> 4) & 3;
#pragma unroll
    for (int j = 0; j < 4; ++j) {
      const int c = c0 + wn + j * 16 + (l & 15);
      const float bv = k_b[c];
#pragma unroll
      for (int i = 0; i < 4; ++i) {
        const int mrow = m0 + wm + i * 16 + q * 4;
#pragma unroll
        for (int r = 0; r < 4; ++r) {
          const int m = mrow + r;
          Kp[pk_off(m >> 4, c >> 5) + ((m & 15) + 16 * ((c >> 3) & 3)) * 8 +
             (c & 7)] = f2bf(acc[i][j][r] + bv);
        }
      }
    }
  } else if (g < 5120) {
    // ---------------- xT branch ----------------
    float (*Ls)[65] = (float (*)[65])smem;  // 64x65 floats = 16640B
    const int gg = g - 1024;
    const int b = gg >> 8;
    const int td = (gg >> 6) & 3;
    const int tn = gg & 63;
    const int nl = t >> 2, dp = (t & 3) * 16;
    const float* src =
        X + ((size_t)b * 4096 + tn * 64 + nl) * 256 + td * 64 + dp;
#pragma unroll
    for (int v = 0; v < 4; ++v) {
      const float4 x = *(const float4*)&src[v * 4];
      Ls[nl][dp + v * 4 + 0] = x.x;
      Ls[nl][dp + v * 4 + 1] = x.y;
      Ls[nl][dp + v * 4 + 2] = x.z;
      Ls[nl][dp + v * 4 + 3] = x.w;
    }
    __syncthreads();
    const int dl = t >> 2, np = (t & 3) * 16;
    u16x8 h0, h1;
#pragma unroll
    for (int j = 0; j < 8; ++j) h0[j] = f2bf(Ls[np + j][dl]);
#pragma unroll
    for (int j = 0; j < 8; ++j) h1[j] = f2bf(Ls[np + 8 + j][dl]);
    const int d = td * 64 + dl;
    const int n0g = tn * 64 + np;
    const int n1g = n0g + 8;
    unsigned short* dst = XTp + (size_t)b * 1048576;
    const size_t o0 = (((size_t)(d >> 4) * 128) + (n0g >> 5)) * 512 +
                      ((d & 15) + 16 * ((n0g >> 3) & 3)) * 8;
    const size_t o1 = (((size_t)(d >> 4) * 128) + (n1g >> 5)) * 512 +
                      ((d & 15) + 16 * ((n1g >> 3) & 3)) * 8;
    *(u16x8*)&dst[o0] = h0;
    *(u16x8*)&dst[o1] = h1;
  } else if (g < 5632) {
    // ---------------- pospool branch (plain partial stores) ----------------
    float4* red4 = (float4*)smem;                 // 256 float4 = 4096B
    float* redc = (float*)(smem + 4096);          // 4 floats
    const int gg = g - 5120;
    const int b = gg >> 5, seg = gg & 31;
    const int dg = t & 63;
    const int nl = t >> 6;
    const int n0 = seg * 128;
    float4 acc = make_float4(0.f, 0.f, 0.f, 0.f);
    float c = 0.f;
    const float* pb = positions + (size_t)b * 4096 * 256;
    for (int j = 0; j < 32; ++j) {
      const int n = n0 + j * 4 + nl;
      const float mf = mask[(size_t)b * 4096 + n] ? 1.f : 0.f;
      const float4 v = *(const float4*)&pb[(size_t)n * 256 + dg * 4];
      acc.x = fmaf(mf, v.x, acc.x);
      acc.y = fmaf(mf, v.y, acc.y);
      acc.z = fmaf(mf, v.z, acc.z);
      acc.w = fmaf(mf, v.w, acc.w);
      c += mf;
    }
    red4[t] = acc;
    if (dg == 0) redc[nl] = c;
    __syncthreads();
    if (t < 64) {
      float4 s = red4[t];
      const float4 s1 = red4[t + 64], s2 = red4[t + 128], s3 = red4[t + 192];
      s.x += s1.x + s2.x + s3.x;
      s.y += s1.y + s2.y + s3.y;
      s.z += s1.z + s2.z + s3.z;
      s.w += s1.w + s2.w + s3.w;
      *(float4*)&ppart[(size_t)(b * 32 + seg) * 256 + t * 4] = s;
      if (t == 0) cpart[b * 32 + seg] = redc[0] + redc[1] + redc[2] + redc[3];
    }
  } else {
    // ---------------- qproj branch ----------------
    float* xs = (float*)smem;  // 256 floats
    const int m = g - 5632;
    const size_t off = pk_off(m >> 4, t >> 5) +
                       ((m & 15) + 16 * ((t >> 3) & 3)) * 8 + (t & 7);
    if (m >= 672) {
      Qp[off] = 0;
      return;
    }
    const float* code;
    const float* W;
    const float* bias;
    if (m < 16)       { code = cat_codes  + m * 256;         W = cat_w;  bias = cat_b; }
    else if (m < 144) { code = type_codes + (m - 16) * 256;  W = type_w; bias = type_b; }
    else if (m < 656) { code = var_codes  + (m - 144) * 256; W = var_w;  bias = var_b; }
    else              { code = sp_codes   + (m - 656) * 256; W = sp_w;   bias = sp_b; }
    xs[t] = code[t];
    __syncthreads();
    float a = bias[t];
    const float* wr = W + (size_t)t * 256;
    for (int k = 0; k < 256; k += 4) {
      const float4 w = *(const float4*)&wr[k];
      a = fmaf(w.x, xs[k], a);
      a = fmaf(w.y, xs[k + 1], a);
      a = fmaf(w.z, xs[k + 2], a);
      a = fmaf(w.w, xs[k + 3], a);
    }
    Qp[off] = f2bf(a);
  }
}

// ---------------------------------------------------------------------------
// attn_fused: grid (32 combos, 11 m-tiles). combo = b*2 + n-slice(2048).
// Per 64-n chunk (32 chunks): K staged 32KB -> LDS via DMA (dbuf); S from
// LDS; P via padded LDS; PLAIN STORES into partials H2[nsl]/lsum2[nsl].
// ---------------------------------------------------------------------------
__global__ __launch_bounds__(256, 2) void attn_fused(
    const unsigned short* __restrict__ Qp, const unsigned short* __restrict__ Kp,
    const unsigned short* __restrict__ XTp,
    const unsigned char* __restrict__ mask, float* __restrict__ H2,
    float* __restrict__ lsum2) {
  __shared__ __align__(16) unsigned short Ks[2][16384];  // 2 x 32KB
  __shared__ __align__(16) unsigned short Plds[64 * 72];
  __shared__ unsigned char msk[2048];
  const int combo = blockIdx.x;
  const int m0 = blockIdx.y * 64;
  const int b = combo >> 1;
  const int nsl = combo & 1;
  const int nbase = nsl * 2048;
  const int t = threadIdx.x, l = t & 63, w = t >> 6;
  const int l15 = l & 15, q = l >> 4;
  ((uint2*)msk)[t] = ((const uint2*)(mask + (size_t)b * 4096 + nbase))[t];
  const int mt_g = (m0 >> 4) + w;
  bf16x8 qf[8];
#pragma unroll
  for (int ks = 0; ks < 8; ++ks)
    qf[ks] = *(const bf16x8*)&Qp[pk_off(mt_g, ks) + l * 8];
  const f32x4 zero = {0.f, 0.f, 0.f, 0.f};
  f32x4 accO[4][4];
#pragma unroll
  for (int i = 0; i < 4; ++i)
#pragma unroll
    for (int j = 0; j < 4; ++j) accO[i][j] = zero;
  f32x4 rs = zero;
  const unsigned short* XTb = XTp + (size_t)b * 1048576;
  // K chunk c is 32KB contiguous at Kp + (b*256 + nbase/16 + 4c)*4096 elems.
  const unsigned short* Kchunk0 = Kp + ((size_t)b * 256 + (nbase >> 4)) * 4096;
  // prologue: DMA chunk 0 into Ks[0]; wave w stages its 8KB quarter
#pragma unroll
  for (int i = 0; i < 8; ++i)
    gl2lds16(Kchunk0 + (w * 8 + i) * 512 + l * 8, &Ks[0][(w * 8 + i) * 512]);
  for (int c = 0; c < 32; ++c) {
    const int cur = c & 1;
    __syncthreads();  // C: drains DMA(c) (vmcnt0) + all waves past PV(c-1)
    // ---- prefetch PV B-fragments (independent; consumed after barrier B) --
    const int nst0 = (nbase >> 5) + c * 2;
    bf16x8 xf[2][4];
#pragma unroll
    for (int ks2 = 0; ks2 < 2; ++ks2)
#pragma unroll
      for (int dj = 0; dj < 4; ++dj)
        xf[ks2][dj] = *(const bf16x8*)&XTb[((size_t)(4 * w + dj) * 128 +
                                            nst0 + ks2) * 512 + l * 8];
    // ---- S phase from LDS ----
    f32x4 accS[4];
#pragma unroll
    for (int f = 0; f < 4; ++f) accS[f] = zero;
#pragma unroll
    for (int ks = 0; ks < 8; ++ks) {
      bf16x8 kf[4];
#pragma unroll
      for (int f = 0; f < 4; ++f)
        kf[f] = *(const bf16x8*)&Ks[cur][(f * 8 + ks) * 512 + l * 8];
#pragma unroll
      for (int f = 0; f < 4; ++f)
        accS[f] = __builtin_amdgcn_mfma_f32_16x16x32_bf16(qf[ks], kf[f],
                                                          accS[f], 0, 0, 0);
    }
    // ---- epilogue: exp + P -> LDS (C-layout rows, stride 72) ----
#pragma unroll
    for (int f = 0; f < 4; ++f) {
      const bool mk = msk[c * 64 + f * 16 + l15] != 0;
#pragma unroll
      for (int r = 0; r < 4; ++r) {
        float s = accS[f][r] * 0.0625f;
        s = fminf(fmaxf(s, -50.f), 50.f);
        if (!mk) s = -50.f;
        const float e = __expf(s);
        Plds[(w * 16 + q * 4 + r) * 72 + f * 16 + l15] = f2bf(e);
        rs[r] += e;
      }
    }
    __syncthreads();  // B: Plds visible (also drains xf loads - needed next)
    // ---- issue DMA for chunk c+1 (drains at next C, hidden behind PV) ----
    if (c < 31) {
      const unsigned short* src = Kchunk0 + (size_t)(c + 1) * 16384;
      unsigned short* dst = &Ks[1 - cur][0];
#pragma unroll
      for (int i = 0; i < 8; ++i)
        gl2lds16(src + (w * 8 + i) * 512 + l * 8, dst + (w * 8 + i) * 512);
    }
    // ---- PV phase ----
#pragma unroll
    for (int ks2 = 0; ks2 < 2; ++ks2) {
      bf16x8 pf[4];
#pragma unroll
      for (int mt = 0; mt < 4; ++mt)
        pf[mt] = *(const bf16x8*)&Plds[(mt * 16 + l15) * 72 + ks2 * 32 + q * 8];
#pragma unroll
      for (int mt = 0; mt < 4; ++mt)
#pragma unroll
        for (int dj = 0; dj < 4; ++dj)
          accO[mt][dj] = __builtin_amdgcn_mfma_f32_16x16x32_bf16(
              pf[mt], xf[ks2][dj], accO[mt][dj], 0, 0, 0);
    }
  }
  // ---- lsum partial: reduce rs over the 16 lanes sharing each row ----
  float* lpart = lsum2 + (size_t)(nsl * 16 + b) * 672;
#pragma unroll
  for (int r = 0; r < 4; ++r) {
    float v = rs[r];
    v += __shfl_xor(v, 1, 64);
    v += __shfl_xor(v, 2, 64);
    v += __shfl_xor(v, 4, 64);
    v += __shfl_xor(v, 8, 64);
    const int m = m0 + w * 16 + q * 4 + r;
    if (l15 == 0 && m < 672) lpart[m] = v;
  }
  // ---- O partial: plain stores into H2[nsl] (no atomics) ----
  float* Hpart = H2 + (size_t)(nsl * 16 + b) * 672 * 256;
#pragma unroll
  for (int mt = 0; mt < 4; ++mt) {
    const int mbase = m0 + mt * 16 + q * 4;
#pragma unroll
    for (int dj = 0; dj < 4; ++dj) {
      const int d = w * 64 + dj * 16 + l15;
#pragma unroll
      for (int r = 0; r < 4; ++r) {
        const int m = mbase + r;
        if (m < 672) Hpart[(size_t)m * 256 + d] = accO[mt][dj][r];
      }
    }
  }
}

// ---------------------------------------------------------------------------
// hnorm (WIDE): wraw[b][m] = ||H2[0]+H2[1]|| * linv / tau; linv = 1/lsum.
// grid (16, 168): wave per m-row, 2688 blocks.
// ---------------------------------------------------------------------------
__global__ __launch_bounds__(256) void hnorm_kern(
    const float* __restrict__ H2, const float* __restrict__ lsum2,
    const float* __restrict__ log_tau, float* __restrict__ linv,
    float* __restrict__ wraw) {
  const int b = blockIdx.x, j = blockIdx.y;
  const int t = threadIdx.x, l = t & 63, w = t >> 6;
  const int m = j * 4 + w;
  const size_t r0 = ((size_t)b * 672 + m) * 256;
  const size_t r1 = ((size_t)(16 + b) * 672 + m) * 256;
  const float4 v0 = *(const float4*)&H2[r0 + l * 4];
  const float4 v1 = *(const float4*)&H2[r1 + l * 4];
  const float sx = v0.x + v1.x, sy = v0.y + v1.y;
  const float sz = v0.z + v1.z, sw = v0.w + v1.w;
  float ss = sx * sx + sy * sy + sz * sz + sw * sw;
#pragma unroll
  for (int s = 1; s < 64; s <<= 1) ss += __shfl_xor(ss, s, 64);
  if (l == 0) {
    const float lt = lsum2[b * 672 + m] + lsum2[(16 + b) * 672 + m];
    const float li = 1.0f / lt;
    const float tau = fminf(fmaxf(expf(log_tau[0]) + 0.1f, 0.1f), 2.0f);
    linv[b * 672 + m] = li;
    wraw[b * 672 + m] = sqrtf(ss) * li / tau;
  }
}

DEV float wave_max(float v) {
#pragma unroll
  for (int m = 1; m < 64; m <<= 1) v = fmaxf(v, __shfl_xor(v, m, 64));
  return v;
}
DEV float wave_sum(float v) {
#pragma unroll
  for (int m = 1; m < 64; m <<= 1) v += __shfl_xor(v, m, 64);
  return v;
}

// ---------------------------------------------------------------------------
// combine: grid (16, 8). Cascade from precomputed wraw (cheap LDS math),
// weights scaled by linv, then the block's 84-m z-slice reading
// H2[0]+H2[1]; plain stores to zpart (zeros where slice empty).
// ---------------------------------------------------------------------------
__global__ __launch_bounds__(256) void combine_kern(
    const float* __restrict__ wraw, const float* __restrict__ linv,
    const float* __restrict__ H2, float* __restrict__ zpart) {
  const int b = blockIdx.x, j = blockIdx.y, t = threadIdx.x, l = t & 63;
  __shared__ float wr[672];
  __shared__ float wsp[672];
  for (int i = t; i < 672; i += 256) wr[i] = wraw[b * 672 + i];
  __syncthreads();
  {
    const float v = (l < 16) ? wr[l] : -1e30f;
    const float mx = wave_max(v);
    const float e = (l < 16) ? expf(wr[l] - mx) : 0.f;
    const float s = wave_sum(e);
    float ww = e / s;
    ww = (ww > 0.1f) ? ww : 0.f;
    const float s2 = wave_sum(ww);
    if (l < 16) wsp[l] = ww / (s2 + 1e-8f);
  }
  __syncthreads();
  {
    const float L0 = wr[16 + l] * wsp[l >> 3];
    const float L1 = wr[16 + 64 + l] * wsp[(64 + l) >> 3];
    const float mx = wave_max(fmaxf(L0, L1));
    const float e0 = expf(L0 - mx), e1 = expf(L1 - mx);
    const float s = wave_sum(e0 + e1);
    float w0 = e0 / s, w1 = e1 / s;
    w0 = (w0 > 0.05f) ? w0 : 0.f;
    w1 = (w1 > 0.05f) ? w1 : 0.f;
    const float s2 = wave_sum(w0 + w1);
    const float inv2 = 1.f / (s2 + 1e-8f);
    wsp[16 + l] = w0 * inv2;
    wsp[16 + 64 + l] = w1 * inv2;
  }
  __syncthreads();
  {
    float Lv[8];
    float lm = -1e30f;
#pragma unroll
    for (int jj = 0; jj < 8; ++jj) {
      const int i = l * 8 + jj;
      Lv[jj] = wr[144 + i] * wsp[16 + (i >> 2)];
      lm = fmaxf(lm, Lv[jj]);
    }
    const float mx = wave_max(lm);
    float ls = 0.f;
#pragma unroll
    for (int jj = 0; jj < 8; ++jj) {
      Lv[jj] = expf(Lv[jj] - mx);
      ls += Lv[jj];
    }
    const float s = wave_sum(ls);
    const float inv = 1.f / s;
    float ls2 = 0.f;
#pragma unroll
    for (int jj = 0; jj < 8; ++jj) {
      float ww = Lv[jj] * inv;
      ww = (ww > 0.025f) ? ww : 0.f;
      Lv[jj] = ww;
      ls2 += ww;
    }
    const float s2 = wave_sum(ls2);
    const float inv2 = 1.f / (s2 + 1e-8f);
#pragma unroll
    for (int jj = 0; jj < 8; ++jj) wsp[144 + l * 8 + jj] = Lv[jj] * inv2;
  }
  __syncthreads();
  {
    const float v = (l < 16) ? wr[656 + l] : -1e30f;
    const float mx = wave_max(v);
    const float e = (l < 16) ? expf(wr[656 + l] - mx) : 0.f;
    const float s = wave_sum(e);
    float ww = e / s;
    ww = (ww > 0.1f) ? ww : 0.f;
    const float s2 = wave_sum(ww);
    if (l < 16) wsp[656 + l] = ww / (s2 + 1e-8f);
  }
  __syncthreads();
  // fold normalization: weight = wsp[m] * linv[b][m]
  for (int i = t; i < 672; i += 256) wsp[i] *= linv[b * 672 + i];
  __syncthreads();
  // ---- this block's 84-m slice of the z-sums, reading H2[0]+H2[1] ----
  const float* Ha = H2 + (size_t)b * 672 * 256;
  const float* Hc = H2 + (size_t)(16 + b) * 672 * 256;
  const int s0 = j * 84, s1 = s0 + 84;
  const int Llo[4] = {0, 16, 144, 656};
  const int Lhi[4] = {16, 144, 656, 672};
#pragma unroll
  for (int lv = 0; lv < 4; ++lv) {
    const int lo = max(s0, Llo[lv]);
    const int hi = min(s1, Lhi[lv]);
    float z = 0.f;
    for (int m = lo; m < hi; ++m)
      z = fmaf(wsp[m], Ha[(size_t)m * 256 + t] + Hc[(size_t)m * 256 + t], z);
    zpart[(((size_t)b * 8 + j) * 4 + lv) * 256 + t] = z;  // 0 where empty
  }
}

// ---------------------------------------------------------------------------
// gate: 1024 threads/block (16 waves = 4/SIMD). Matvec rows split 4-way:
// thread = row*4 + part, 32 float4 loads each, LDS partial reduce. Cuts the
// serial load chain 4x and quadruples waves/CU vs the 256-thread version
// (which measured ~150us latency-bound at 1 wave/SIMD). grid 16.
// ---------------------------------------------------------------------------
__global__ __launch_bounds__(1024) void gate_kern(
    const float* __restrict__ zpart, const float* __restrict__ ppart,
    const float* __restrict__ cpart, const float* __restrict__ g1_w,
    const float* __restrict__ g1_b, const float* __restrict__ g2_w,
    const float* __restrict__ g2_b, const float* __restrict__ out_w,
    const float* __restrict__ out_b, const float* __restrict__ ln_g,
    const float* __restrict__ ln_b, const float* __restrict__ lvlw,
    float* __restrict__ out) {
  const int b = blockIdx.x, t = threadIdx.x;
  __shared__ float gin[512];
  __shared__ float zvs[4][256];
  __shared__ float hb[256];
  __shared__ float zc[256];
  __shared__ float oar[256];
  __shared__ float red[256];
  __shared__ float par[1024];
  __shared__ float cred;
  // ---- zpart reduce: thread = lv*256 + tt ----
  {
    const int lv = t >> 8, tt = t & 255;
    float z = 0.f;
#pragma unroll
    for (int jj = 0; jj < 8; ++jj)
      z += zpart[(((size_t)b * 8 + jj) * 4 + lv) * 256 + tt];
    zvs[lv][tt] = z;
  }
  if (t == 0) {
    float c = 0.f;
    for (int seg = 0; seg < 32; ++seg) c += cpart[b * 32 + seg];
    cred = fmaxf(c, 1.0f);
  }
  __syncthreads();
  if (t < 256) {
    float pa = 0.f;
    for (int seg = 0; seg < 32; ++seg)
      pa += ppart[(size_t)(b * 32 + seg) * 256 + t];
    gin[256 + t] = pa / cred;
    gin[t] = zvs[0][t];
  }
  __syncthreads();
  // ---- g1: 256 rows x 512, 4-way split ----
  {
    const int r = t >> 2, p = t & 3;
    const float* w1 = g1_w + (size_t)r * 512 + p * 128;
    const float* gv = gin + p * 128;
    float a = 0.f;
    for (int k = 0; k < 128; k += 4) {
      const float4 w = *(const float4*)&w1[k];
      a = fmaf(w.x, gv[k], a);
      a = fmaf(w.y, gv[k + 1], a);
      a = fmaf(w.z, gv[k + 2], a);
      a = fmaf(w.w, gv[k + 3], a);
    }
    par[t] = a;
  }
  __syncthreads();
  if (t < 256) {
    const float a =
        par[t * 4] + par[t * 4 + 1] + par[t * 4 + 2] + par[t * 4 + 3] +
        g1_b[t];
    hb[t] = 0.5f * a * (1.0f + erff(a * 0.7071067811865475f));
  }
  __syncthreads();
  // ---- g2: 256 rows x 256, 4-way split ----
  {
    const int r = t >> 2, p = t & 3;
    const float* w2 = g2_w + (size_t)r * 256 + p * 64;
    const float* hv = hb + p * 64;
    float a = 0.f;
    for (int k = 0; k < 64; k += 4) {
      const float4 w = *(const float4*)&w2[k];
      a = fmaf(w.x, hv[k], a);
      a = fmaf(w.y, hv[k + 1], a);
      a = fmaf(w.z, hv[k + 2], a);
      a = fmaf(w.w, hv[k + 3], a);
    }
    par[t] = a;
  }
  __syncthreads();
  if (t < 256) {
    const float a2 =
        par[t * 4] + par[t * 4 + 1] + par[t * 4 + 2] + par[t * 4 + 3] +
        g2_b[t];
    const float pg = 1.0f / (1.0f + expf(-a2));
    const float l0 = lvlw[0], l1 = lvlw[1], l2 = lvlw[2], l3 = lvlw[3];
    const float mx = fmaxf(fmaxf(l0, l1), fmaxf(l2, l3));
    const float e0 = expf(l0 - mx), e1 = expf(l1 - mx);
    const float e2 = expf(l2 - mx), e3 = expf(l3 - mx);
    const float einv = 1.0f / (e0 + e1 + e2 + e3);
    zc[t] = (e0 * zvs[0][t] * pg + e1 * zvs[1][t] + e2 * zvs[2][t] +
             e3 * zvs[3][t]) *
            einv;
  }
  __syncthreads();
  // ---- out proj: 256 rows x 256, 4-way split ----
  {
    const int r = t >> 2, p = t & 3;
    const float* wo = out_w + (size_t)r * 256 + p * 64;
    const float* zv = zc + p * 64;
    float a = 0.f;
    for (int k = 0; k < 64; k += 4) {
      const float4 w = *(const float4*)&wo[k];
      a = fmaf(w.x, zv[k], a);
      a = fmaf(w.y, zv[k + 1], a);
      a = fmaf(w.z, zv[k + 2], a);
      a = fmaf(w.w, zv[k + 3], a);
    }
    par[t] = a;
  }
  __syncthreads();
  if (t < 256) {
    const float o =
        par[t * 4] + par[t * 4 + 1] + par[t * 4 + 2] + par[t * 4 + 3] +
        out_b[t];
    oar[t] = o;
    red[t] = o;
  }
  __syncthreads();
  for (int s = 128; s > 0; s >>= 1) {
    if (t < s) red[t] += red[t + s];
    __syncthreads();
  }
  const float mu = red[0] / 256.f;
  __syncthreads();
  if (t < 256) red[t] = oar[t] * oar[t];
  __syncthreads();
  for (int s = 128; s > 0; s >>= 1) {
    if (t < s) red[t] += red[t + s];
    __syncthreads();
  }
  if (t < 256) {
    const float var = red[0] / 256.f - mu * mu;
    out[b * 256 + t] = (oar[t] - mu) * rsqrtf(var + 1e-5f) * ln_g[t] + ln_b[t];
  }
}

// ---------------------------------------------------------------------------
// launch — 5 dispatches, 0 memsets.
// ---------------------------------------------------------------------------
extern "C" void kernel_launch(void* const* d_in, const int* in_sizes, int n_in,
                              void* d_out, int out_size, void* d_ws,
                              size_t ws_size, hipStream_t stream) {
  (void)in_sizes; (void)n_in; (void)out_size; (void)ws_size;
  const float* X          = (const float*)d_in[0];
  const float* positions  = (const float*)d_in[1];
  const float* cat_codes  = (const float*)d_in[2];
  const float* type_codes = (const float*)d_in[3];
  const float* var_codes  = (const float*)d_in[4];
  const float* sp_codes   = (const float*)d_in[5];
  const float* log_tau    = (const float*)d_in[6];
  const float* cat_w      = (const float*)d_in[7];
  const float* cat_b      = (const float*)d_in[8];
  const float* type_w     = (const float*)d_in[9];
  const float* type_b     = (const float*)d_in[10];
  const float* var_w      = (const float*)d_in[11];
  const float* var_b      = (const float*)d_in[12];
  const float* sp_w       = (const float*)d_in[13];
  const float* sp_b       = (const float*)d_in[14];
  const float* k_w        = (const float*)d_in[15];
  const float* k_b        = (const float*)d_in[16];
  const float* g1_w       = (const float*)d_in[17];
  const float* g1_b       = (const float*)d_in[18];
  const float* g2_w       = (const float*)d_in[19];
  const float* g2_b       = (const float*)d_in[20];
  const float* out_w      = (const float*)d_in[21];
  const float* out_b      = (const float*)d_in[22];
  const float* ln_g       = (const float*)d_in[23];
  const float* ln_b       = (const float*)d_in[24];
  const float* lvlw       = (const float*)d_in[25];
  const unsigned char* mask = (const unsigned char*)d_in[26];

  char* ws = (char*)d_ws;
  constexpr size_t O_KP  = 0;          // bf16 Kpack [4096][512]   = 33,554,432
  constexpr size_t O_XT  = 33554432;   // bf16 XTpack              = 33,554,432
  constexpr size_t O_QP  = 67108864;   // bf16 Qpack               = 360,448
  constexpr size_t O_H2  = 67469312;   // f32 H2 [2][16][672][256] = 22,020,096
  constexpr size_t O_L2  = 89489408;   // f32 lsum2 [2][16][672]   = 86,016
  constexpr size_t O_PP  = 89575424;   // f32 ppart [512][256]     = 524,288
  constexpr size_t O_CP  = 90099712;   // f32 cpart [512]          = 2,048
  constexpr size_t O_ZP  = 90101760;   // f32 zpart [16][8][4][256]= 524,288
  constexpr size_t O_LI  = 90626048;   // f32 linv [16][672]       = 43,008
  constexpr size_t O_WR  = 90669056;   // f32 wraw [16][672]       = 43,008

  unsigned short* Kp  = (unsigned short*)(ws + O_KP);
  unsigned short* XTp = (unsigned short*)(ws + O_XT);
  unsigned short* Qp  = (unsigned short*)(ws + O_QP);
  float* H2           = (float*)(ws + O_H2);
  float* lsum2        = (float*)(ws + O_L2);
  float* ppart        = (float*)(ws + O_PP);
  float* cpart        = (float*)(ws + O_CP);
  float* zpart        = (float*)(ws + O_ZP);
  float* linv         = (float*)(ws + O_LI);
  float* wraw         = (float*)(ws + O_WR);
  float* out          = (float*)d_out;

  // one launch for kproj (1024) + xT (4096) + pospool (512) + qproj (704)
  fused_pre<<<dim3(6336), 256, 0, stream>>>(
      X, k_w, k_b, Kp, XTp, positions, mask, ppart, cpart, cat_codes,
      type_codes, var_codes, sp_codes, cat_w, cat_b, type_w, type_b, var_w,
      var_b, sp_w, sp_b, Qp);

  attn_fused<<<dim3(32, 11), 256, 0, stream>>>(Qp, Kp, XTp, mask, H2, lsum2);

  hnorm_kern<<<dim3(16, 168), 256, 0, stream>>>(H2, lsum2, log_tau, linv,
                                                wraw);

  combine_kern<<<dim3(16, 8), 256, 0, stream>>>(wraw, linv, H2, zpart);

  gate_kern<<<dim3(16), 1024, 0, stream>>>(zpart, ppart, cpart, g1_w, g1_b,
                                           g2_w, g2_b, out_w, out_b, ln_g,
                                           ln_b, lvlw, out);
}